// Round 1
// baseline (1233.770 us; speedup 1.0000x reference)
//
#include <hip/hip_runtime.h>

#define N_NODES 50000
#define N_EDGES 640000
#define D 128
#define OUT0_ELEMS (N_NODES * D)   // h_neighbor
// d_out layout: [0, OUT0_ELEMS) = h_neighbor, [OUT0_ELEMS, 2*OUT0_ELEMS) = out

// ---------------------------------------------------------------------------
// Kernel 1: edge scatter.  32 threads per edge, each thread owns one float4
// (4 consecutive feats).  Reads nfeat[src] row (512B, coalesced across the
// 32-lane half-wave), scales by w[e], atomicAdds into hn[dst].
// ---------------------------------------------------------------------------
__global__ __launch_bounds__(256) void edge_scatter(
    const float* __restrict__ nfeat, const float* __restrict__ w,
    const int* __restrict__ src, const int* __restrict__ dst,
    float* __restrict__ hn) {
  int tid = blockIdx.x * 256 + threadIdx.x;
  int e = tid >> 5;
  if (e >= N_EDGES) return;
  int q = tid & 31;  // float4 index within the 128-float row
  int s = src[e];
  int d = dst[e];
  float we = w[e];
  float4 v = ((const float4*)(nfeat + (size_t)s * D))[q];
  float* drow = hn + (size_t)d * D + q * 4;
  atomicAdd(drow + 0, v.x * we);
  atomicAdd(drow + 1, v.y * we);
  atomicAdd(drow + 2, v.z * we);
  atomicAdd(drow + 3, v.w * we);
}

// ---------------------------------------------------------------------------
// Kernel 2: bi-interaction.  Block = 256 threads = 4 waves; lanes = nodes
// (64 nodes per block).  Wave `wid` computes outputs [wid*32, wid*32+32).
// Each lane streams its node's h/hn rows as float4 from global (L1-resident),
// W1/W2 fetched as wave-uniform scalar loads (readfirstlane-forced) so the
// vector pipe does only FMAs.  leaky_relu + add epilogue fused, float4 store.
// ---------------------------------------------------------------------------
__global__ __launch_bounds__(256) void bi_inter(
    const float* __restrict__ h, const float* __restrict__ hn,
    const float* __restrict__ W1, const float* __restrict__ W2,
    float* __restrict__ out) {
  int wid = __builtin_amdgcn_readfirstlane(threadIdx.x >> 6);
  int lane = threadIdx.x & 63;
  int node = blockIdx.x * 64 + lane;
  if (node >= N_NODES) return;  // no barriers below, safe

  const float4* h4 = (const float4*)(h + (size_t)node * D);
  const float4* n4 = (const float4*)(hn + (size_t)node * D);

  float acc1[32];
  float acc2[32];
#pragma unroll
  for (int j = 0; j < 32; ++j) { acc1[j] = 0.f; acc2[j] = 0.f; }

  const int obase = wid * 32;

  for (int kq = 0; kq < 32; ++kq) {  // 32 float4 chunks over K=128
    float4 hv = h4[kq];
    float4 nv = n4[kq];
    float a0 = hv.x + nv.x, a1 = hv.y + nv.y, a2 = hv.z + nv.z, a3 = hv.w + nv.w;
    float m0 = hv.x * nv.x, m1 = hv.y * nv.y, m2 = hv.z * nv.z, m3 = hv.w * nv.w;
#pragma unroll
    for (int j = 0; j < 32; ++j) {
      int o = obase + j;
      float4 w1 = *(const float4*)(W1 + (size_t)o * D + kq * 4);
      float4 w2 = *(const float4*)(W2 + (size_t)o * D + kq * 4);
      acc1[j] += a0 * w1.x + a1 * w1.y + a2 * w1.z + a3 * w1.w;
      acc2[j] += m0 * w2.x + m1 * w2.y + m2 * w2.z + m3 * w2.w;
    }
  }

  float* orow = out + (size_t)node * D + obase;
#pragma unroll
  for (int j = 0; j < 32; j += 4) {
    float4 r;
    float x;
    x = acc1[j + 0]; x = x > 0.f ? x : 0.01f * x;
    r.x = x; x = acc2[j + 0]; x = x > 0.f ? x : 0.01f * x; r.x += x;
    x = acc1[j + 1]; x = x > 0.f ? x : 0.01f * x;
    r.y = x; x = acc2[j + 1]; x = x > 0.f ? x : 0.01f * x; r.y += x;
    x = acc1[j + 2]; x = x > 0.f ? x : 0.01f * x;
    r.z = x; x = acc2[j + 2]; x = x > 0.f ? x : 0.01f * x; r.z += x;
    x = acc1[j + 3]; x = x > 0.f ? x : 0.01f * x;
    r.w = x; x = acc2[j + 3]; x = x > 0.f ? x : 0.01f * x; r.w += x;
    *(float4*)(orow + j) = r;
  }
}

extern "C" void kernel_launch(void* const* d_in, const int* in_sizes, int n_in,
                              void* d_out, int out_size, void* d_ws, size_t ws_size,
                              hipStream_t stream) {
  const float* nfeat = (const float*)d_in[0];
  const float* w     = (const float*)d_in[1];
  const float* W1    = (const float*)d_in[2];
  const float* W2    = (const float*)d_in[3];
  const int*   src   = (const int*)d_in[4];
  const int*   dst   = (const int*)d_in[5];

  float* hn  = (float*)d_out;               // output 0: h_neighbor
  float* out = (float*)d_out + OUT0_ELEMS;  // output 1: bi-interaction result

  // h_neighbor accumulates via atomics -> must be zeroed every call.
  hipMemsetAsync(hn, 0, (size_t)OUT0_ELEMS * sizeof(float), stream);

  // Edge scatter: 32 threads/edge.
  {
    long long threads = (long long)N_EDGES * 32;
    int blocks = (int)((threads + 255) / 256);
    edge_scatter<<<blocks, 256, 0, stream>>>(nfeat, w, src, dst, hn);
  }

  // Bi-interaction GEMMs: 64 nodes per block.
  {
    int blocks = (N_NODES + 63) / 64;
    bi_inter<<<blocks, 256, 0, stream>>>(nfeat, hn, W1, W2, out);
  }
}

// Round 2
// 280.693 us; speedup vs baseline: 4.3954x; 4.3954x over previous
//
#include <hip/hip_runtime.h>

#define N_NODES 50000
#define N_EDGES 640000
#define D 128
#define OUT0_ELEMS (N_NODES * D)
#define SCAN_BLOCKS ((N_NODES + 255) / 256)   // 196

// ---------------------------------------------------------------------------
// CSR build + gather replaces the float-atomic scatter (was 1072us, atomic-
// write-through bound: WRITE_SIZE 1.28GB for 328MB of payload).
// ---------------------------------------------------------------------------

__global__ __launch_bounds__(256) void hist_kernel(
    const int* __restrict__ dst, int* __restrict__ cnt) {
  int e = blockIdx.x * 256 + threadIdx.x;
  if (e >= N_EDGES) return;
  atomicAdd(&cnt[dst[e]], 1);
}

// Per-block exclusive scan of cnt -> offs (block-local), block totals -> bsums.
__global__ __launch_bounds__(256) void scan_block(
    const int* __restrict__ cnt, int* __restrict__ offs, int* __restrict__ bsums) {
  __shared__ int sdata[256];
  int t = threadIdx.x;
  int i = blockIdx.x * 256 + t;
  int v = (i < N_NODES) ? cnt[i] : 0;
  sdata[t] = v;
  __syncthreads();
#pragma unroll
  for (int off = 1; off < 256; off <<= 1) {
    int x = (t >= off) ? sdata[t - off] : 0;
    __syncthreads();
    sdata[t] += x;
    __syncthreads();
  }
  if (i < N_NODES) offs[i] = sdata[t] - v;  // exclusive within block
  if (t == 255) bsums[blockIdx.x] = sdata[t];
}

// Single-block exclusive scan of the 196 block sums, in place.
__global__ __launch_bounds__(256) void scan_top(int* __restrict__ bsums) {
  __shared__ int sdata[256];
  int t = threadIdx.x;
  int v = (t < SCAN_BLOCKS) ? bsums[t] : 0;
  sdata[t] = v;
  __syncthreads();
#pragma unroll
  for (int off = 1; off < 256; off <<= 1) {
    int x = (t >= off) ? sdata[t - off] : 0;
    __syncthreads();
    sdata[t] += x;
    __syncthreads();
  }
  if (t < SCAN_BLOCKS) bsums[t] = sdata[t] - v;
}

__global__ __launch_bounds__(256) void scan_finalize(
    int* __restrict__ offs, const int* __restrict__ bsums, int* __restrict__ cursor) {
  int i = blockIdx.x * 256 + threadIdx.x;
  if (i >= N_NODES) return;
  int o = offs[i] + bsums[blockIdx.x];
  offs[i] = o;
  cursor[i] = o;
  if (i == N_NODES - 1) offs[N_NODES] = N_EDGES;
}

// Bucket the edges by dst: sorted (src, w) pairs.
__global__ __launch_bounds__(256) void fill_kernel(
    const int* __restrict__ src, const int* __restrict__ dst,
    const float* __restrict__ w, int* __restrict__ cursor,
    int* __restrict__ ssrc, float* __restrict__ sw) {
  int e = blockIdx.x * 256 + threadIdx.x;
  if (e >= N_EDGES) return;
  int d = dst[e];
  int pos = atomicAdd(&cursor[d], 1);
  ssrc[pos] = src[e];
  sw[pos] = w[e];
}

// Gather: half-wave (32 threads) per destination node, each lane owns one
// float4 chunk of the 128-float row.  Unroll-2 over incident edges for ILP.
__global__ __launch_bounds__(256) void gather_kernel(
    const float* __restrict__ nfeat, const int* __restrict__ offs,
    const int* __restrict__ ssrc, const float* __restrict__ sw,
    float* __restrict__ hn) {
  int tid = blockIdx.x * 256 + threadIdx.x;
  int node = tid >> 5;
  if (node >= N_NODES) return;
  int q = tid & 31;
  int beg = offs[node];
  int end = offs[node + 1];
  float4 acc = {0.f, 0.f, 0.f, 0.f};
  int k = beg;
  for (; k + 1 < end; k += 2) {
    int s0 = ssrc[k], s1 = ssrc[k + 1];
    float w0 = sw[k], w1 = sw[k + 1];
    float4 v0 = ((const float4*)(nfeat + (size_t)s0 * D))[q];
    float4 v1 = ((const float4*)(nfeat + (size_t)s1 * D))[q];
    acc.x += v0.x * w0 + v1.x * w1;
    acc.y += v0.y * w0 + v1.y * w1;
    acc.z += v0.z * w0 + v1.z * w1;
    acc.w += v0.w * w0 + v1.w * w1;
  }
  if (k < end) {
    int s0 = ssrc[k];
    float w0 = sw[k];
    float4 v0 = ((const float4*)(nfeat + (size_t)s0 * D))[q];
    acc.x += v0.x * w0;
    acc.y += v0.y * w0;
    acc.z += v0.z * w0;
    acc.w += v0.w * w0;
  }
  ((float4*)(hn + (size_t)node * D))[q] = acc;
}

// ---------------------------------------------------------------------------
// Fallback scatter (round-1 path) if workspace is too small.
// ---------------------------------------------------------------------------
__global__ __launch_bounds__(256) void edge_scatter(
    const float* __restrict__ nfeat, const float* __restrict__ w,
    const int* __restrict__ src, const int* __restrict__ dst,
    float* __restrict__ hn) {
  int tid = blockIdx.x * 256 + threadIdx.x;
  int e = tid >> 5;
  if (e >= N_EDGES) return;
  int q = tid & 31;
  int s = src[e];
  int d = dst[e];
  float we = w[e];
  float4 v = ((const float4*)(nfeat + (size_t)s * D))[q];
  float* drow = hn + (size_t)d * D + q * 4;
  atomicAdd(drow + 0, v.x * we);
  atomicAdd(drow + 1, v.y * we);
  atomicAdd(drow + 2, v.z * we);
  atomicAdd(drow + 3, v.w * we);
}

// ---------------------------------------------------------------------------
// Bi-interaction (unchanged from round 1; optimize next round with counters).
// ---------------------------------------------------------------------------
__global__ __launch_bounds__(256) void bi_inter(
    const float* __restrict__ h, const float* __restrict__ hn,
    const float* __restrict__ W1, const float* __restrict__ W2,
    float* __restrict__ out) {
  int wid = __builtin_amdgcn_readfirstlane(threadIdx.x >> 6);
  int lane = threadIdx.x & 63;
  int node = blockIdx.x * 64 + lane;
  if (node >= N_NODES) return;

  const float4* h4 = (const float4*)(h + (size_t)node * D);
  const float4* n4 = (const float4*)(hn + (size_t)node * D);

  float acc1[32];
  float acc2[32];
#pragma unroll
  for (int j = 0; j < 32; ++j) { acc1[j] = 0.f; acc2[j] = 0.f; }

  const int obase = wid * 32;

  for (int kq = 0; kq < 32; ++kq) {
    float4 hv = h4[kq];
    float4 nv = n4[kq];
    float a0 = hv.x + nv.x, a1 = hv.y + nv.y, a2 = hv.z + nv.z, a3 = hv.w + nv.w;
    float m0 = hv.x * nv.x, m1 = hv.y * nv.y, m2 = hv.z * nv.z, m3 = hv.w * nv.w;
#pragma unroll
    for (int j = 0; j < 32; ++j) {
      int o = obase + j;
      float4 w1 = *(const float4*)(W1 + (size_t)o * D + kq * 4);
      float4 w2 = *(const float4*)(W2 + (size_t)o * D + kq * 4);
      acc1[j] += a0 * w1.x + a1 * w1.y + a2 * w1.z + a3 * w1.w;
      acc2[j] += m0 * w2.x + m1 * w2.y + m2 * w2.z + m3 * w2.w;
    }
  }

  float* orow = out + (size_t)node * D + obase;
#pragma unroll
  for (int j = 0; j < 32; j += 4) {
    float4 r;
    float x;
    x = acc1[j + 0]; x = x > 0.f ? x : 0.01f * x;
    r.x = x; x = acc2[j + 0]; x = x > 0.f ? x : 0.01f * x; r.x += x;
    x = acc1[j + 1]; x = x > 0.f ? x : 0.01f * x;
    r.y = x; x = acc2[j + 1]; x = x > 0.f ? x : 0.01f * x; r.y += x;
    x = acc1[j + 2]; x = x > 0.f ? x : 0.01f * x;
    r.z = x; x = acc2[j + 2]; x = x > 0.f ? x : 0.01f * x; r.z += x;
    x = acc1[j + 3]; x = x > 0.f ? x : 0.01f * x;
    r.w = x; x = acc2[j + 3]; x = x > 0.f ? x : 0.01f * x; r.w += x;
    *(float4*)(orow + j) = r;
  }
}

extern "C" void kernel_launch(void* const* d_in, const int* in_sizes, int n_in,
                              void* d_out, int out_size, void* d_ws, size_t ws_size,
                              hipStream_t stream) {
  const float* nfeat = (const float*)d_in[0];
  const float* w     = (const float*)d_in[1];
  const float* W1    = (const float*)d_in[2];
  const float* W2    = (const float*)d_in[3];
  const int*   src   = (const int*)d_in[4];
  const int*   dst   = (const int*)d_in[5];

  float* hn  = (float*)d_out;
  float* out = (float*)d_out + OUT0_ELEMS;

  // Workspace layout (all 4B-aligned; total ~5.7 MB)
  char* ws = (char*)d_ws;
  size_t off = 0;
  int* cnt = (int*)(ws + off);      off += (size_t)N_NODES * 4;
  int* offs = (int*)(ws + off);     off += (size_t)(N_NODES + 1) * 4;
  int* cursor = (int*)(ws + off);   off += (size_t)N_NODES * 4;
  int* bsums = (int*)(ws + off);    off += 256 * 4;
  int* ssrc = (int*)(ws + off);     off += (size_t)N_EDGES * 4;
  float* sw = (float*)(ws + off);   off += (size_t)N_EDGES * 4;

  if (ws_size < off) {
    // Fallback: atomic scatter (round-1 path).
    hipMemsetAsync(hn, 0, (size_t)OUT0_ELEMS * sizeof(float), stream);
    long long threads = (long long)N_EDGES * 32;
    int blocks = (int)((threads + 255) / 256);
    edge_scatter<<<blocks, 256, 0, stream>>>(nfeat, w, src, dst, hn);
  } else {
    hipMemsetAsync(cnt, 0, (size_t)N_NODES * 4, stream);
    hist_kernel<<<(N_EDGES + 255) / 256, 256, 0, stream>>>(dst, cnt);
    scan_block<<<SCAN_BLOCKS, 256, 0, stream>>>(cnt, offs, bsums);
    scan_top<<<1, 256, 0, stream>>>(bsums);
    scan_finalize<<<SCAN_BLOCKS, 256, 0, stream>>>(offs, bsums, cursor);
    fill_kernel<<<(N_EDGES + 255) / 256, 256, 0, stream>>>(src, dst, w, cursor, ssrc, sw);
    gather_kernel<<<(N_NODES * 32 + 255) / 256, 256, 0, stream>>>(nfeat, offs, ssrc, sw, hn);
  }

  bi_inter<<<(N_NODES + 63) / 64, 256, 0, stream>>>(nfeat, hn, W1, W2, out);
}

// Round 3
// 162.470 us; speedup vs baseline: 7.5939x; 1.7277x over previous
//
#include <hip/hip_runtime.h>
#include <hip/hip_bf16.h>

#define N_NODES 50000
#define N_EDGES 640000
#define D 128
#define OUT0_ELEMS (N_NODES * D)
#define SCAN_BLOCKS ((N_NODES + 255) / 256)   // 196

typedef __attribute__((ext_vector_type(8))) short short8v;   // 8 bf16 (4 VGPR)
typedef __attribute__((ext_vector_type(4))) short short4v;   // 4 bf16 (8B)
typedef __attribute__((ext_vector_type(4))) float f32x4;

static __device__ __forceinline__ unsigned short f2bf(float x) {
  __hip_bfloat16 b = __float2bfloat16(x);   // RNE
  return *reinterpret_cast<unsigned short*>(&b);
}

// ---------------------------------------------------------------------------
// CSR build (unchanged from round 2).
// ---------------------------------------------------------------------------
__global__ __launch_bounds__(256) void hist_kernel(
    const int* __restrict__ dst, int* __restrict__ cnt) {
  int e = blockIdx.x * 256 + threadIdx.x;
  if (e >= N_EDGES) return;
  atomicAdd(&cnt[dst[e]], 1);
}

__global__ __launch_bounds__(256) void scan_block(
    const int* __restrict__ cnt, int* __restrict__ offs, int* __restrict__ bsums) {
  __shared__ int sdata[256];
  int t = threadIdx.x;
  int i = blockIdx.x * 256 + t;
  int v = (i < N_NODES) ? cnt[i] : 0;
  sdata[t] = v;
  __syncthreads();
#pragma unroll
  for (int off = 1; off < 256; off <<= 1) {
    int x = (t >= off) ? sdata[t - off] : 0;
    __syncthreads();
    sdata[t] += x;
    __syncthreads();
  }
  if (i < N_NODES) offs[i] = sdata[t] - v;
  if (t == 255) bsums[blockIdx.x] = sdata[t];
}

__global__ __launch_bounds__(256) void scan_top(int* __restrict__ bsums) {
  __shared__ int sdata[256];
  int t = threadIdx.x;
  int v = (t < SCAN_BLOCKS) ? bsums[t] : 0;
  sdata[t] = v;
  __syncthreads();
#pragma unroll
  for (int off = 1; off < 256; off <<= 1) {
    int x = (t >= off) ? sdata[t - off] : 0;
    __syncthreads();
    sdata[t] += x;
    __syncthreads();
  }
  if (t < SCAN_BLOCKS) bsums[t] = sdata[t] - v;
}

__global__ __launch_bounds__(256) void scan_finalize(
    int* __restrict__ offs, const int* __restrict__ bsums, int* __restrict__ cursor) {
  int i = blockIdx.x * 256 + threadIdx.x;
  if (i >= N_NODES) return;
  int o = offs[i] + bsums[blockIdx.x];
  offs[i] = o;
  cursor[i] = o;
  if (i == N_NODES - 1) offs[N_NODES] = N_EDGES;
}

__global__ __launch_bounds__(256) void fill_kernel(
    const int* __restrict__ src, const int* __restrict__ dst,
    const float* __restrict__ w, int* __restrict__ cursor,
    int* __restrict__ ssrc, float* __restrict__ sw) {
  int e = blockIdx.x * 256 + threadIdx.x;
  if (e >= N_EDGES) return;
  int d = dst[e];
  int pos = atomicAdd(&cursor[d], 1);
  ssrc[pos] = src[e];
  sw[pos] = w[e];
}

__global__ __launch_bounds__(256) void gather_kernel(
    const float* __restrict__ nfeat, const int* __restrict__ offs,
    const int* __restrict__ ssrc, const float* __restrict__ sw,
    float* __restrict__ hn) {
  int tid = blockIdx.x * 256 + threadIdx.x;
  int node = tid >> 5;
  if (node >= N_NODES) return;
  int q = tid & 31;
  int beg = offs[node];
  int end = offs[node + 1];
  float4 acc = {0.f, 0.f, 0.f, 0.f};
  int k = beg;
  for (; k + 1 < end; k += 2) {
    int s0 = ssrc[k], s1 = ssrc[k + 1];
    float w0 = sw[k], w1 = sw[k + 1];
    float4 v0 = ((const float4*)(nfeat + (size_t)s0 * D))[q];
    float4 v1 = ((const float4*)(nfeat + (size_t)s1 * D))[q];
    acc.x += v0.x * w0 + v1.x * w1;
    acc.y += v0.y * w0 + v1.y * w1;
    acc.z += v0.z * w0 + v1.z * w1;
    acc.w += v0.w * w0 + v1.w * w1;
  }
  if (k < end) {
    int s0 = ssrc[k];
    float w0 = sw[k];
    float4 v0 = ((const float4*)(nfeat + (size_t)s0 * D))[q];
    acc.x += v0.x * w0;
    acc.y += v0.y * w0;
    acc.z += v0.z * w0;
    acc.w += v0.w * w0;
  }
  ((float4*)(hn + (size_t)node * D))[q] = acc;
}

// ---------------------------------------------------------------------------
// W f32 -> bf16 once per launch (both matrices). 32K elements, trivial.
// ---------------------------------------------------------------------------
__global__ __launch_bounds__(256) void wconv(
    const float* __restrict__ W1, const float* __restrict__ W2,
    unsigned short* __restrict__ wc) {
  int i = blockIdx.x * 256 + threadIdx.x;
  if (i >= D * D) return;
  wc[i] = f2bf(W1[i]);
  wc[D * D + i] = f2bf(W2[i]);
}

// ---------------------------------------------------------------------------
// Bi-interaction via 16x16x32 bf16 MFMA.  Block = 256 thr = 4 waves = 64 rows.
// A1=h+hn, A2=h*hn staged in LDS (bf16, XOR-swizzled: row-major D=128 is a
// multi-way bank conflict on ds_read_b128 otherwise).  W frags (B operand,
// W is [out][in] = [N][K] row-major = exactly the B^T layout MFMA wants)
// held in registers: 16 frags x 4 VGPR = 64 VGPR.  Wave wid owns output
// cols [32*wid, 32*wid+32).  Fused leaky_relu + add epilogue.
// ---------------------------------------------------------------------------
__global__ __launch_bounds__(256) void bi_mfma(
    const float* __restrict__ h, const float* __restrict__ hn,
    const unsigned short* __restrict__ wc, float* __restrict__ out) {
  __shared__ __align__(16) unsigned short lds[2 * 64 * D];  // 32 KiB

  const int tid = threadIdx.x;
  const int lane = tid & 63;
  const int wid = tid >> 6;
  const int base = blockIdx.x * 64;
  const int r16 = lane & 15;
  const int kg = lane >> 4;   // 0..3

  // B fragments from global (L2-resident 64KB): lane holds col=c0+(lane&15),
  // k = ks*32 + (lane>>4)*8 .. +8 (contiguous -> one 16B load).
  short8v bf[2][2][4];
  {
    const int colbase = wid * 32;
#pragma unroll
    for (int g = 0; g < 2; ++g)
#pragma unroll
      for (int c = 0; c < 2; ++c)
#pragma unroll
        for (int ks = 0; ks < 4; ++ks) {
          int col = colbase + c * 16 + r16;
          int k = ks * 32 + kg * 8;
          bf[g][c][ks] =
              *(const short8v*)(wc + (size_t)g * D * D + (size_t)col * D + k);
        }
  }

  // Stage A1, A2 into LDS as bf16 with XOR swizzle (byte ^= (row&7)<<4).
#pragma unroll
  for (int p = 0; p < 8; ++p) {
    int flat = p * 1024 + tid * 4;        // 0..8191 f32 elements
    int row = flat >> 7;
    int col = flat & 127;
    int node = base + row;
    float4 hv = make_float4(0.f, 0.f, 0.f, 0.f);
    float4 nv = make_float4(0.f, 0.f, 0.f, 0.f);
    if (node < N_NODES) {
      hv = *(const float4*)(h + (size_t)node * D + col);
      nv = *(const float4*)(hn + (size_t)node * D + col);
    }
    short4v av, mv;
    av[0] = (short)f2bf(hv.x + nv.x);
    av[1] = (short)f2bf(hv.y + nv.y);
    av[2] = (short)f2bf(hv.z + nv.z);
    av[3] = (short)f2bf(hv.w + nv.w);
    mv[0] = (short)f2bf(hv.x * nv.x);
    mv[1] = (short)f2bf(hv.y * nv.y);
    mv[2] = (short)f2bf(hv.z * nv.z);
    mv[3] = (short)f2bf(hv.w * nv.w);
    int boff = (row * 256 + col * 2) ^ ((row & 7) << 4);
    *(short4v*)((char*)lds + boff) = av;
    *(short4v*)((char*)lds + 16384 + boff) = mv;
  }
  __syncthreads();

  f32x4 acc1[4][2], acc2[4][2];
#pragma unroll
  for (int rt = 0; rt < 4; ++rt)
#pragma unroll
    for (int c = 0; c < 2; ++c) {
      acc1[rt][c] = (f32x4){0.f, 0.f, 0.f, 0.f};
      acc2[rt][c] = (f32x4){0.f, 0.f, 0.f, 0.f};
    }

#pragma unroll
  for (int ks = 0; ks < 4; ++ks) {
#pragma unroll
    for (int rt = 0; rt < 4; ++rt) {
      int row = rt * 16 + r16;
      int boff = (row * 256 + (ks * 32 + kg * 8) * 2) ^ ((row & 7) << 4);
      short8v a1 = *(const short8v*)((const char*)lds + boff);
      short8v a2 = *(const short8v*)((const char*)lds + 16384 + boff);
#pragma unroll
      for (int c = 0; c < 2; ++c) {
        acc1[rt][c] = __builtin_amdgcn_mfma_f32_16x16x32_bf16(
            a1, bf[0][c][ks], acc1[rt][c], 0, 0, 0);
        acc2[rt][c] = __builtin_amdgcn_mfma_f32_16x16x32_bf16(
            a2, bf[1][c][ks], acc2[rt][c], 0, 0, 0);
      }
    }
  }

  // Epilogue. C/D mapping: col = lane&15, row = (lane>>4)*4 + reg.
#pragma unroll
  for (int rt = 0; rt < 4; ++rt) {
#pragma unroll
    for (int c = 0; c < 2; ++c) {
#pragma unroll
      for (int e = 0; e < 4; ++e) {
        int row = rt * 16 + kg * 4 + e;
        int node = base + row;
        if (node < N_NODES) {
          int col = wid * 32 + c * 16 + r16;
          float x1 = acc1[rt][c][e];
          float x2 = acc2[rt][c][e];
          x1 = x1 > 0.f ? x1 : 0.01f * x1;
          x2 = x2 > 0.f ? x2 : 0.01f * x2;
          out[(size_t)node * D + col] = x1 + x2;
        }
      }
    }
  }
}

// ---------------------------------------------------------------------------
// Fallback (round-1 paths) if workspace too small.
// ---------------------------------------------------------------------------
__global__ __launch_bounds__(256) void edge_scatter(
    const float* __restrict__ nfeat, const float* __restrict__ w,
    const int* __restrict__ src, const int* __restrict__ dst,
    float* __restrict__ hn) {
  int tid = blockIdx.x * 256 + threadIdx.x;
  int e = tid >> 5;
  if (e >= N_EDGES) return;
  int q = tid & 31;
  int s = src[e];
  int d = dst[e];
  float we = w[e];
  float4 v = ((const float4*)(nfeat + (size_t)s * D))[q];
  float* drow = hn + (size_t)d * D + q * 4;
  atomicAdd(drow + 0, v.x * we);
  atomicAdd(drow + 1, v.y * we);
  atomicAdd(drow + 2, v.z * we);
  atomicAdd(drow + 3, v.w * we);
}

__global__ __launch_bounds__(256) void bi_inter(
    const float* __restrict__ h, const float* __restrict__ hn,
    const float* __restrict__ W1, const float* __restrict__ W2,
    float* __restrict__ out) {
  int wid = __builtin_amdgcn_readfirstlane(threadIdx.x >> 6);
  int lane = threadIdx.x & 63;
  int node = blockIdx.x * 64 + lane;
  if (node >= N_NODES) return;
  const float4* h4 = (const float4*)(h + (size_t)node * D);
  const float4* n4 = (const float4*)(hn + (size_t)node * D);
  float acc1[32], acc2[32];
#pragma unroll
  for (int j = 0; j < 32; ++j) { acc1[j] = 0.f; acc2[j] = 0.f; }
  const int obase = wid * 32;
  for (int kq = 0; kq < 32; ++kq) {
    float4 hv = h4[kq];
    float4 nv = n4[kq];
    float a0 = hv.x + nv.x, a1 = hv.y + nv.y, a2 = hv.z + nv.z, a3 = hv.w + nv.w;
    float m0 = hv.x * nv.x, m1 = hv.y * nv.y, m2 = hv.z * nv.z, m3 = hv.w * nv.w;
#pragma unroll
    for (int j = 0; j < 32; ++j) {
      int o = obase + j;
      float4 w1 = *(const float4*)(W1 + (size_t)o * D + kq * 4);
      float4 w2 = *(const float4*)(W2 + (size_t)o * D + kq * 4);
      acc1[j] += a0 * w1.x + a1 * w1.y + a2 * w1.z + a3 * w1.w;
      acc2[j] += m0 * w2.x + m1 * w2.y + m2 * w2.z + m3 * w2.w;
    }
  }
  float* orow = out + (size_t)node * D + obase;
#pragma unroll
  for (int j = 0; j < 32; j += 4) {
    float4 r;
    float x;
    x = acc1[j + 0]; x = x > 0.f ? x : 0.01f * x;
    r.x = x; x = acc2[j + 0]; x = x > 0.f ? x : 0.01f * x; r.x += x;
    x = acc1[j + 1]; x = x > 0.f ? x : 0.01f * x;
    r.y = x; x = acc2[j + 1]; x = x > 0.f ? x : 0.01f * x; r.y += x;
    x = acc1[j + 2]; x = x > 0.f ? x : 0.01f * x;
    r.z = x; x = acc2[j + 2]; x = x > 0.f ? x : 0.01f * x; r.z += x;
    x = acc1[j + 3]; x = x > 0.f ? x : 0.01f * x;
    r.w = x; x = acc2[j + 3]; x = x > 0.f ? x : 0.01f * x; r.w += x;
    *(float4*)(orow + j) = r;
  }
}

extern "C" void kernel_launch(void* const* d_in, const int* in_sizes, int n_in,
                              void* d_out, int out_size, void* d_ws, size_t ws_size,
                              hipStream_t stream) {
  const float* nfeat = (const float*)d_in[0];
  const float* w     = (const float*)d_in[1];
  const float* W1    = (const float*)d_in[2];
  const float* W2    = (const float*)d_in[3];
  const int*   src   = (const int*)d_in[4];
  const int*   dst   = (const int*)d_in[5];

  float* hn  = (float*)d_out;
  float* out = (float*)d_out + OUT0_ELEMS;

  // Workspace layout (~5.8 MB)
  char* ws = (char*)d_ws;
  size_t off = 0;
  int* cnt = (int*)(ws + off);      off += (size_t)N_NODES * 4;
  int* offs = (int*)(ws + off);     off += (size_t)(N_NODES + 1) * 4;
  int* cursor = (int*)(ws + off);   off += (size_t)N_NODES * 4;
  int* bsums = (int*)(ws + off);    off += 256 * 4;
  int* ssrc = (int*)(ws + off);     off += (size_t)N_EDGES * 4;
  float* sw = (float*)(ws + off);   off += (size_t)N_EDGES * 4;
  off = (off + 63) & ~(size_t)63;   // 16B+ alignment for bf16 W frags
  unsigned short* wc = (unsigned short*)(ws + off);
  off += (size_t)2 * D * D * 2;

  if (ws_size < off) {
    // Fallback: round-1 path.
    hipMemsetAsync(hn, 0, (size_t)OUT0_ELEMS * sizeof(float), stream);
    long long threads = (long long)N_EDGES * 32;
    int blocks = (int)((threads + 255) / 256);
    edge_scatter<<<blocks, 256, 0, stream>>>(nfeat, w, src, dst, hn);
    bi_inter<<<(N_NODES + 63) / 64, 256, 0, stream>>>(nfeat, hn, W1, W2, out);
    return;
  }

  wconv<<<(D * D + 255) / 256, 256, 0, stream>>>(W1, W2, wc);
  hipMemsetAsync(cnt, 0, (size_t)N_NODES * 4, stream);
  hist_kernel<<<(N_EDGES + 255) / 256, 256, 0, stream>>>(dst, cnt);
  scan_block<<<SCAN_BLOCKS, 256, 0, stream>>>(cnt, offs, bsums);
  scan_top<<<1, 256, 0, stream>>>(bsums);
  scan_finalize<<<SCAN_BLOCKS, 256, 0, stream>>>(offs, bsums, cursor);
  fill_kernel<<<(N_EDGES + 255) / 256, 256, 0, stream>>>(src, dst, w, cursor, ssrc, sw);
  gather_kernel<<<(N_NODES * 32 + 255) / 256, 256, 0, stream>>>(nfeat, offs, ssrc, sw, hn);
  bi_mfma<<<(N_NODES + 63) / 64, 256, 0, stream>>>(nfeat, hn, wc, out);
}

// Round 4
// 134.296 us; speedup vs baseline: 9.1870x; 1.2098x over previous
//
#include <hip/hip_runtime.h>
#include <hip/hip_bf16.h>

#define N_NODES 50000
#define N_EDGES 640000
#define D 128
#define OUT0_ELEMS (N_NODES * D)
#define SCAN_BLOCKS ((N_NODES + 255) / 256)   // 196

typedef __attribute__((ext_vector_type(8))) short short8v;   // 8 bf16
typedef __attribute__((ext_vector_type(4))) short short4v;   // 4 bf16
typedef __attribute__((ext_vector_type(4))) float f32x4;

static __device__ __forceinline__ unsigned short f2bf(float x) {
  __hip_bfloat16 b = __float2bfloat16(x);   // RNE
  return *reinterpret_cast<unsigned short*>(&b);
}
static __device__ __forceinline__ float bf2f(unsigned short u) {
  unsigned x = ((unsigned)u) << 16;
  return __builtin_bit_cast(float, x);
}

// ---------------------------------------------------------------------------
// One-pass conversions: nfeat f32->bf16 (12.8 MB) + W1,W2 f32->bf16.
// ---------------------------------------------------------------------------
__global__ __launch_bounds__(256) void conv_all(
    const float* __restrict__ nfeat, const float* __restrict__ W1,
    const float* __restrict__ W2, unsigned short* __restrict__ nf16,
    unsigned short* __restrict__ wc) {
  int i = blockIdx.x * 256 + threadIdx.x;           // 800000 threads
  int base = i * 8;
  float4 a = *(const float4*)(nfeat + base);
  float4 b = *(const float4*)(nfeat + base + 4);
  short8v o;
  o[0] = (short)f2bf(a.x); o[1] = (short)f2bf(a.y);
  o[2] = (short)f2bf(a.z); o[3] = (short)f2bf(a.w);
  o[4] = (short)f2bf(b.x); o[5] = (short)f2bf(b.y);
  o[6] = (short)f2bf(b.z); o[7] = (short)f2bf(b.w);
  *(short8v*)(nf16 + base) = o;
  if (i < D * D) {
    wc[i] = f2bf(W1[i]);
    wc[D * D + i] = f2bf(W2[i]);
  }
}

// ---------------------------------------------------------------------------
// CSR build.
// ---------------------------------------------------------------------------
__global__ __launch_bounds__(256) void hist_kernel(
    const int* __restrict__ dst, int* __restrict__ cnt) {
  int e = blockIdx.x * 256 + threadIdx.x;
  if (e >= N_EDGES) return;
  atomicAdd(&cnt[dst[e]], 1);
}

__global__ __launch_bounds__(256) void scan_block(
    const int* __restrict__ cnt, int* __restrict__ offs, int* __restrict__ bsums) {
  __shared__ int sdata[256];
  int t = threadIdx.x;
  int i = blockIdx.x * 256 + t;
  int v = (i < N_NODES) ? cnt[i] : 0;
  sdata[t] = v;
  __syncthreads();
#pragma unroll
  for (int off = 1; off < 256; off <<= 1) {
    int x = (t >= off) ? sdata[t - off] : 0;
    __syncthreads();
    sdata[t] += x;
    __syncthreads();
  }
  if (i < N_NODES) offs[i] = sdata[t] - v;
  if (t == 255) bsums[blockIdx.x] = sdata[t];
}

__global__ __launch_bounds__(256) void scan_top(int* __restrict__ bsums) {
  __shared__ int sdata[256];
  int t = threadIdx.x;
  int v = (t < SCAN_BLOCKS) ? bsums[t] : 0;
  sdata[t] = v;
  __syncthreads();
#pragma unroll
  for (int off = 1; off < 256; off <<= 1) {
    int x = (t >= off) ? sdata[t - off] : 0;
    __syncthreads();
    sdata[t] += x;
    __syncthreads();
  }
  if (t < SCAN_BLOCKS) bsums[t] = sdata[t] - v;
}

__global__ __launch_bounds__(256) void scan_finalize(
    int* __restrict__ offs, const int* __restrict__ bsums, int* __restrict__ cursor) {
  int i = blockIdx.x * 256 + threadIdx.x;
  if (i >= N_NODES) return;
  int o = offs[i] + bsums[blockIdx.x];
  offs[i] = o;
  cursor[i] = o;
  if (i == N_NODES - 1) offs[N_NODES] = N_EDGES;
}

// Bucket edges by dst; pack (src, w) into one 8B record.
__global__ __launch_bounds__(256) void fill_kernel(
    const int* __restrict__ src, const int* __restrict__ dst,
    const float* __restrict__ w, int* __restrict__ cursor,
    int2* __restrict__ es) {
  int e = blockIdx.x * 256 + threadIdx.x;
  if (e >= N_EDGES) return;
  int d = dst[e];
  int pos = atomicAdd(&cursor[d], 1);
  es[pos] = make_int2(src[e], __float_as_int(w[e]));
}

// ---------------------------------------------------------------------------
// Gather, bf16 rows: 16 lanes per node, lane owns 8 bf16 (16B load/edge),
// unroll-4 over edges for memory-level parallelism.  f32 accumulate.
// ---------------------------------------------------------------------------
__global__ __launch_bounds__(256) void gather_bf16(
    const unsigned short* __restrict__ nf16, const int* __restrict__ offs,
    const int2* __restrict__ es, float* __restrict__ hn) {
  int tid = blockIdx.x * 256 + threadIdx.x;
  int node = tid >> 4;
  if (node >= N_NODES) return;
  int q = tid & 15;                   // owns bf16 [8q, 8q+8)
  int beg = offs[node];
  int end = offs[node + 1];
  float acc[8];
#pragma unroll
  for (int j = 0; j < 8; ++j) acc[j] = 0.f;

  int k = beg;
  for (; k + 3 < end; k += 4) {
    int2 p0 = es[k], p1 = es[k + 1], p2 = es[k + 2], p3 = es[k + 3];
    short8v v0 = *(const short8v*)(nf16 + (size_t)p0.x * D + q * 8);
    short8v v1 = *(const short8v*)(nf16 + (size_t)p1.x * D + q * 8);
    short8v v2 = *(const short8v*)(nf16 + (size_t)p2.x * D + q * 8);
    short8v v3 = *(const short8v*)(nf16 + (size_t)p3.x * D + q * 8);
    float w0 = __int_as_float(p0.y), w1 = __int_as_float(p1.y);
    float w2 = __int_as_float(p2.y), w3 = __int_as_float(p3.y);
#pragma unroll
    for (int j = 0; j < 8; ++j) {
      acc[j] += bf2f((unsigned short)v0[j]) * w0;
      acc[j] += bf2f((unsigned short)v1[j]) * w1;
      acc[j] += bf2f((unsigned short)v2[j]) * w2;
      acc[j] += bf2f((unsigned short)v3[j]) * w3;
    }
  }
  for (; k < end; ++k) {
    int2 p0 = es[k];
    short8v v0 = *(const short8v*)(nf16 + (size_t)p0.x * D + q * 8);
    float w0 = __int_as_float(p0.y);
#pragma unroll
    for (int j = 0; j < 8; ++j) acc[j] += bf2f((unsigned short)v0[j]) * w0;
  }

  float* orow = hn + (size_t)node * D + q * 8;
  *(float4*)(orow) = make_float4(acc[0], acc[1], acc[2], acc[3]);
  *(float4*)(orow + 4) = make_float4(acc[4], acc[5], acc[6], acc[7]);
}

// f32 gather kept for the mid-tier fallback.
__global__ __launch_bounds__(256) void gather_f32(
    const float* __restrict__ nfeat, const int* __restrict__ offs,
    const int2* __restrict__ es, float* __restrict__ hn) {
  int tid = blockIdx.x * 256 + threadIdx.x;
  int node = tid >> 5;
  if (node >= N_NODES) return;
  int q = tid & 31;
  int beg = offs[node];
  int end = offs[node + 1];
  float4 acc = {0.f, 0.f, 0.f, 0.f};
  int k = beg;
  for (; k + 1 < end; k += 2) {
    int2 p0 = es[k], p1 = es[k + 1];
    float w0 = __int_as_float(p0.y), w1 = __int_as_float(p1.y);
    float4 v0 = ((const float4*)(nfeat + (size_t)p0.x * D))[q];
    float4 v1 = ((const float4*)(nfeat + (size_t)p1.x * D))[q];
    acc.x += v0.x * w0 + v1.x * w1;
    acc.y += v0.y * w0 + v1.y * w1;
    acc.z += v0.z * w0 + v1.z * w1;
    acc.w += v0.w * w0 + v1.w * w1;
  }
  if (k < end) {
    int2 p0 = es[k];
    float w0 = __int_as_float(p0.y);
    float4 v0 = ((const float4*)(nfeat + (size_t)p0.x * D))[q];
    acc.x += v0.x * w0;
    acc.y += v0.y * w0;
    acc.z += v0.z * w0;
    acc.w += v0.w * w0;
  }
  ((float4*)(hn + (size_t)node * D))[q] = acc;
}

__global__ __launch_bounds__(256) void wconv(
    const float* __restrict__ W1, const float* __restrict__ W2,
    unsigned short* __restrict__ wc) {
  int i = blockIdx.x * 256 + threadIdx.x;
  if (i >= D * D) return;
  wc[i] = f2bf(W1[i]);
  wc[D * D + i] = f2bf(W2[i]);
}

// ---------------------------------------------------------------------------
// Bi-interaction via 16x16x32 bf16 MFMA (templated on h dtype).
// Block = 4 waves = 64 rows; wave wid owns output cols [32*wid, 32*wid+32).
// A1=h+hn, A2=h*hn staged bf16 in LDS with XOR swizzle; W frags in regs.
// ---------------------------------------------------------------------------
template <bool HBF16>
__global__ __launch_bounds__(256) void bi_mfma(
    const void* __restrict__ hsrc, const float* __restrict__ hn,
    const unsigned short* __restrict__ wc, float* __restrict__ out) {
  __shared__ __align__(16) unsigned short lds[2 * 64 * D];  // 32 KiB

  const int tid = threadIdx.x;
  const int lane = tid & 63;
  const int wid = tid >> 6;
  const int base = blockIdx.x * 64;
  const int r16 = lane & 15;
  const int kg = lane >> 4;

  short8v bf[2][2][4];
  {
    const int colbase = wid * 32;
#pragma unroll
    for (int g = 0; g < 2; ++g)
#pragma unroll
      for (int c = 0; c < 2; ++c)
#pragma unroll
        for (int ks = 0; ks < 4; ++ks) {
          int col = colbase + c * 16 + r16;
          int k = ks * 32 + kg * 8;
          bf[g][c][ks] =
              *(const short8v*)(wc + (size_t)g * D * D + (size_t)col * D + k);
        }
  }

#pragma unroll
  for (int p = 0; p < 8; ++p) {
    int flat = p * 1024 + tid * 4;
    int row = flat >> 7;
    int col = flat & 127;
    int node = base + row;
    float hx0 = 0.f, hx1 = 0.f, hx2 = 0.f, hx3 = 0.f;
    float4 nv = make_float4(0.f, 0.f, 0.f, 0.f);
    if (node < N_NODES) {
      if constexpr (HBF16) {
        short4v hv =
            *(const short4v*)((const unsigned short*)hsrc + (size_t)node * D + col);
        hx0 = bf2f((unsigned short)hv[0]);
        hx1 = bf2f((unsigned short)hv[1]);
        hx2 = bf2f((unsigned short)hv[2]);
        hx3 = bf2f((unsigned short)hv[3]);
      } else {
        float4 hv = *(const float4*)((const float*)hsrc + (size_t)node * D + col);
        hx0 = hv.x; hx1 = hv.y; hx2 = hv.z; hx3 = hv.w;
      }
      nv = *(const float4*)(hn + (size_t)node * D + col);
    }
    short4v av, mv;
    av[0] = (short)f2bf(hx0 + nv.x);
    av[1] = (short)f2bf(hx1 + nv.y);
    av[2] = (short)f2bf(hx2 + nv.z);
    av[3] = (short)f2bf(hx3 + nv.w);
    mv[0] = (short)f2bf(hx0 * nv.x);
    mv[1] = (short)f2bf(hx1 * nv.y);
    mv[2] = (short)f2bf(hx2 * nv.z);
    mv[3] = (short)f2bf(hx3 * nv.w);
    int boff = (row * 256 + col * 2) ^ ((row & 7) << 4);
    *(short4v*)((char*)lds + boff) = av;
    *(short4v*)((char*)lds + 16384 + boff) = mv;
  }
  __syncthreads();

  f32x4 acc1[4][2], acc2[4][2];
#pragma unroll
  for (int rt = 0; rt < 4; ++rt)
#pragma unroll
    for (int c = 0; c < 2; ++c) {
      acc1[rt][c] = (f32x4){0.f, 0.f, 0.f, 0.f};
      acc2[rt][c] = (f32x4){0.f, 0.f, 0.f, 0.f};
    }

#pragma unroll
  for (int ks = 0; ks < 4; ++ks) {
#pragma unroll
    for (int rt = 0; rt < 4; ++rt) {
      int row = rt * 16 + r16;
      int boff = (row * 256 + (ks * 32 + kg * 8) * 2) ^ ((row & 7) << 4);
      short8v a1 = *(const short8v*)((const char*)lds + boff);
      short8v a2 = *(const short8v*)((const char*)lds + 16384 + boff);
#pragma unroll
      for (int c = 0; c < 2; ++c) {
        acc1[rt][c] = __builtin_amdgcn_mfma_f32_16x16x32_bf16(
            a1, bf[0][c][ks], acc1[rt][c], 0, 0, 0);
        acc2[rt][c] = __builtin_amdgcn_mfma_f32_16x16x32_bf16(
            a2, bf[1][c][ks], acc2[rt][c], 0, 0, 0);
      }
    }
  }

#pragma unroll
  for (int rt = 0; rt < 4; ++rt) {
#pragma unroll
    for (int c = 0; c < 2; ++c) {
#pragma unroll
      for (int e = 0; e < 4; ++e) {
        int row = rt * 16 + kg * 4 + e;
        int node = base + row;
        if (node < N_NODES) {
          int col = wid * 32 + c * 16 + r16;
          float x1 = acc1[rt][c][e];
          float x2 = acc2[rt][c][e];
          x1 = x1 > 0.f ? x1 : 0.01f * x1;
          x2 = x2 > 0.f ? x2 : 0.01f * x2;
          out[(size_t)node * D + col] = x1 + x2;
        }
      }
    }
  }
}

// ---------------------------------------------------------------------------
// Tier-0 fallback (round-1 path).
// ---------------------------------------------------------------------------
__global__ __launch_bounds__(256) void edge_scatter(
    const float* __restrict__ nfeat, const float* __restrict__ w,
    const int* __restrict__ src, const int* __restrict__ dst,
    float* __restrict__ hn) {
  int tid = blockIdx.x * 256 + threadIdx.x;
  int e = tid >> 5;
  if (e >= N_EDGES) return;
  int q = tid & 31;
  int s = src[e];
  int d = dst[e];
  float we = w[e];
  float4 v = ((const float4*)(nfeat + (size_t)s * D))[q];
  float* drow = hn + (size_t)d * D + q * 4;
  atomicAdd(drow + 0, v.x * we);
  atomicAdd(drow + 1, v.y * we);
  atomicAdd(drow + 2, v.z * we);
  atomicAdd(drow + 3, v.w * we);
}

__global__ __launch_bounds__(256) void bi_inter(
    const float* __restrict__ h, const float* __restrict__ hn,
    const float* __restrict__ W1, const float* __restrict__ W2,
    float* __restrict__ out) {
  int wid = __builtin_amdgcn_readfirstlane(threadIdx.x >> 6);
  int lane = threadIdx.x & 63;
  int node = blockIdx.x * 64 + lane;
  if (node >= N_NODES) return;
  const float4* h4 = (const float4*)(h + (size_t)node * D);
  const float4* n4 = (const float4*)(hn + (size_t)node * D);
  float acc1[32], acc2[32];
#pragma unroll
  for (int j = 0; j < 32; ++j) { acc1[j] = 0.f; acc2[j] = 0.f; }
  const int obase = wid * 32;
  for (int kq = 0; kq < 32; ++kq) {
    float4 hv = h4[kq];
    float4 nv = n4[kq];
    float a0 = hv.x + nv.x, a1 = hv.y + nv.y, a2 = hv.z + nv.z, a3 = hv.w + nv.w;
    float m0 = hv.x * nv.x, m1 = hv.y * nv.y, m2 = hv.z * nv.z, m3 = hv.w * nv.w;
#pragma unroll
    for (int j = 0; j < 32; ++j) {
      int o = obase + j;
      float4 w1 = *(const float4*)(W1 + (size_t)o * D + kq * 4);
      float4 w2 = *(const float4*)(W2 + (size_t)o * D + kq * 4);
      acc1[j] += a0 * w1.x + a1 * w1.y + a2 * w1.z + a3 * w1.w;
      acc2[j] += m0 * w2.x + m1 * w2.y + m2 * w2.z + m3 * w2.w;
    }
  }
  float* orow = out + (size_t)node * D + obase;
#pragma unroll
  for (int j = 0; j < 32; j += 4) {
    float4 r;
    float x;
    x = acc1[j + 0]; x = x > 0.f ? x : 0.01f * x;
    r.x = x; x = acc2[j + 0]; x = x > 0.f ? x : 0.01f * x; r.x += x;
    x = acc1[j + 1]; x = x > 0.f ? x : 0.01f * x;
    r.y = x; x = acc2[j + 1]; x = x > 0.f ? x : 0.01f * x; r.y += x;
    x = acc1[j + 2]; x = x > 0.f ? x : 0.01f * x;
    r.z = x; x = acc2[j + 2]; x = x > 0.f ? x : 0.01f * x; r.z += x;
    x = acc1[j + 3]; x = x > 0.f ? x : 0.01f * x;
    r.w = x; x = acc2[j + 3]; x = x > 0.f ? x : 0.01f * x; r.w += x;
    *(float4*)(orow + j) = r;
  }
}

extern "C" void kernel_launch(void* const* d_in, const int* in_sizes, int n_in,
                              void* d_out, int out_size, void* d_ws, size_t ws_size,
                              hipStream_t stream) {
  const float* nfeat = (const float*)d_in[0];
  const float* w     = (const float*)d_in[1];
  const float* W1    = (const float*)d_in[2];
  const float* W2    = (const float*)d_in[3];
  const int*   src   = (const int*)d_in[4];
  const int*   dst   = (const int*)d_in[5];

  float* hn  = (float*)d_out;
  float* out = (float*)d_out + OUT0_ELEMS;

  // Workspace layout
  char* ws = (char*)d_ws;
  size_t off = 0;
  int* cnt = (int*)(ws + off);      off += (size_t)N_NODES * 4;
  int* offs = (int*)(ws + off);     off += (size_t)(N_NODES + 1) * 4;
  int* cursor = (int*)(ws + off);   off += (size_t)N_NODES * 4;
  int* bsums = (int*)(ws + off);    off += 256 * 4;
  int2* es = (int2*)(ws + off);     off += (size_t)N_EDGES * 8;
  off = (off + 63) & ~(size_t)63;
  unsigned short* wc = (unsigned short*)(ws + off);
  off += (size_t)2 * D * D * 2;
  size_t tier1_bytes = off;
  off = (off + 63) & ~(size_t)63;
  unsigned short* nf16 = (unsigned short*)(ws + off);
  off += (size_t)N_NODES * D * 2;
  size_t tier2_bytes = off;

  if (ws_size < tier1_bytes) {
    // Tier 0: atomic scatter + VALU GEMM.
    hipMemsetAsync(hn, 0, (size_t)OUT0_ELEMS * sizeof(float), stream);
    long long threads = (long long)N_EDGES * 32;
    int blocks = (int)((threads + 255) / 256);
    edge_scatter<<<blocks, 256, 0, stream>>>(nfeat, w, src, dst, hn);
    bi_inter<<<(N_NODES + 63) / 64, 256, 0, stream>>>(nfeat, hn, W1, W2, out);
    return;
  }

  bool full = (ws_size >= tier2_bytes);

  if (full) {
    conv_all<<<(N_NODES * D / 8 + 255) / 256, 256, 0, stream>>>(
        nfeat, W1, W2, nf16, wc);
  } else {
    wconv<<<(D * D + 255) / 256, 256, 0, stream>>>(W1, W2, wc);
  }
  hipMemsetAsync(cnt, 0, (size_t)N_NODES * 4, stream);
  hist_kernel<<<(N_EDGES + 255) / 256, 256, 0, stream>>>(dst, cnt);
  scan_block<<<SCAN_BLOCKS, 256, 0, stream>>>(cnt, offs, bsums);
  scan_top<<<1, 256, 0, stream>>>(bsums);
  scan_finalize<<<SCAN_BLOCKS, 256, 0, stream>>>(offs, bsums, cursor);
  fill_kernel<<<(N_EDGES + 255) / 256, 256, 0, stream>>>(src, dst, w, cursor, es);

  if (full) {
    gather_bf16<<<(N_NODES * 16 + 255) / 256, 256, 0, stream>>>(nf16, offs, es, hn);
    bi_mfma<true><<<(N_NODES + 63) / 64, 256, 0, stream>>>(nf16, hn, wc, out);
  } else {
    gather_f32<<<(N_NODES * 32 + 255) / 256, 256, 0, stream>>>(nfeat, offs, es, hn);
    bi_mfma<false><<<(N_NODES + 63) / 64, 256, 0, stream>>>(nfeat, hn, wc, out);
  }
}

// Round 5
// 111.113 us; speedup vs baseline: 11.1038x; 1.2086x over previous
//
#include <hip/hip_runtime.h>
#include <hip/hip_bf16.h>

#define N_NODES 50000
#define N_EDGES 640000
#define D 128
#define OUT0_ELEMS (N_NODES * D)
#define SCAN_BLOCKS ((N_NODES + 255) / 256)   // 196

typedef __attribute__((ext_vector_type(8))) short short8v;   // 8 bf16
typedef __attribute__((ext_vector_type(4))) short short4v;   // 4 bf16
typedef __attribute__((ext_vector_type(4))) float f32x4;

static __device__ __forceinline__ unsigned short f2bf(float x) {
  __hip_bfloat16 b = __float2bfloat16(x);   // RNE
  return *reinterpret_cast<unsigned short*>(&b);
}
static __device__ __forceinline__ float bf2f(unsigned short u) {
  unsigned x = ((unsigned)u) << 16;
  return __builtin_bit_cast(float, x);
}
// Edge record: (bf16(w) << 16) | src   (src < 50000 < 2^16)
static __device__ __forceinline__ unsigned pack_edge(int s, float wv) {
  return ((unsigned)f2bf(wv) << 16) | (unsigned)s;
}

// ---------------------------------------------------------------------------
// conv_all: nfeat f32->bf16 (12.8MB), W1/W2 f32->bf16, and zero cnt.
// 3125 blocks x 256 thr, 8 elems each = exactly N_NODES*D.
// ---------------------------------------------------------------------------
__global__ __launch_bounds__(256) void conv_all(
    const float* __restrict__ nfeat, const float* __restrict__ W1,
    const float* __restrict__ W2, unsigned short* __restrict__ nf16,
    unsigned short* __restrict__ wc, int* __restrict__ cnt) {
  int i = blockIdx.x * 256 + threadIdx.x;
  int base = i * 8;
  float4 a = *(const float4*)(nfeat + base);
  float4 b = *(const float4*)(nfeat + base + 4);
  short8v o;
  o[0] = (short)f2bf(a.x); o[1] = (short)f2bf(a.y);
  o[2] = (short)f2bf(a.z); o[3] = (short)f2bf(a.w);
  o[4] = (short)f2bf(b.x); o[5] = (short)f2bf(b.y);
  o[6] = (short)f2bf(b.z); o[7] = (short)f2bf(b.w);
  *(short8v*)(nf16 + base) = o;
  if (i < D * D) {
    wc[i] = f2bf(W1[i]);
    wc[D * D + i] = f2bf(W2[i]);
  }
  if (i < N_NODES) cnt[i] = 0;
}

// ---------------------------------------------------------------------------
// hist + rank in one pass: rank[e] = fetch-add(cnt[dst[e]]).
// 4 edges/thread (int4 loads, int4 rank store).  625 blocks exactly.
// ---------------------------------------------------------------------------
__global__ __launch_bounds__(256) void hist_rank(
    const int* __restrict__ dst, int* __restrict__ cnt, int* __restrict__ rank) {
  int t = blockIdx.x * 256 + threadIdx.x;
  int e = t * 4;
  if (e >= N_EDGES) return;
  int4 d4 = *(const int4*)(dst + e);
  int4 r4;
  r4.x = atomicAdd(&cnt[d4.x], 1);
  r4.y = atomicAdd(&cnt[d4.y], 1);
  r4.z = atomicAdd(&cnt[d4.z], 1);
  r4.w = atomicAdd(&cnt[d4.w], 1);
  *(int4*)(rank + e) = r4;
}

// ---------------------------------------------------------------------------
// Scan (3 small kernels, as before).
// ---------------------------------------------------------------------------
__global__ __launch_bounds__(256) void scan_block(
    const int* __restrict__ cnt, int* __restrict__ offs, int* __restrict__ bsums) {
  __shared__ int sdata[256];
  int t = threadIdx.x;
  int i = blockIdx.x * 256 + t;
  int v = (i < N_NODES) ? cnt[i] : 0;
  sdata[t] = v;
  __syncthreads();
#pragma unroll
  for (int off = 1; off < 256; off <<= 1) {
    int x = (t >= off) ? sdata[t - off] : 0;
    __syncthreads();
    sdata[t] += x;
    __syncthreads();
  }
  if (i < N_NODES) offs[i] = sdata[t] - v;
  if (t == 255) bsums[blockIdx.x] = sdata[t];
}

__global__ __launch_bounds__(256) void scan_top(int* __restrict__ bsums) {
  __shared__ int sdata[256];
  int t = threadIdx.x;
  int v = (t < SCAN_BLOCKS) ? bsums[t] : 0;
  sdata[t] = v;
  __syncthreads();
#pragma unroll
  for (int off = 1; off < 256; off <<= 1) {
    int x = (t >= off) ? sdata[t - off] : 0;
    __syncthreads();
    sdata[t] += x;
    __syncthreads();
  }
  if (t < SCAN_BLOCKS) bsums[t] = sdata[t] - v;
}

__global__ __launch_bounds__(256) void scan_finalize(
    int* __restrict__ offs, const int* __restrict__ bsums) {
  int i = blockIdx.x * 256 + threadIdx.x;
  if (i >= N_NODES) return;
  offs[i] += bsums[blockIdx.x];
  if (i == N_NODES - 1) offs[N_NODES] = N_EDGES;
}

// ---------------------------------------------------------------------------
// fill4: atomic-free scatter of packed 4B records. 4 edges/thread.
// ---------------------------------------------------------------------------
__global__ __launch_bounds__(256) void fill4(
    const int* __restrict__ src, const int* __restrict__ dst,
    const float* __restrict__ w, const int* __restrict__ rank,
    const int* __restrict__ offs, unsigned* __restrict__ es) {
  int t = blockIdx.x * 256 + threadIdx.x;
  int e = t * 4;
  if (e >= N_EDGES) return;
  int4 d4 = *(const int4*)(dst + e);
  int4 r4 = *(const int4*)(rank + e);
  int4 s4 = *(const int4*)(src + e);
  float4 w4 = *(const float4*)(w + e);
  es[offs[d4.x] + r4.x] = pack_edge(s4.x, w4.x);
  es[offs[d4.y] + r4.y] = pack_edge(s4.y, w4.y);
  es[offs[d4.z] + r4.z] = pack_edge(s4.z, w4.z);
  es[offs[d4.w] + r4.w] = pack_edge(s4.w, w4.w);
}

// ---------------------------------------------------------------------------
// Gather, bf16 rows, 4B edge records: 16 lanes/node, lane owns 8 bf16,
// unroll-4 over edges.  f32 accumulate, f32 hn output.
// ---------------------------------------------------------------------------
__global__ __launch_bounds__(256) void gather_bf16(
    const unsigned short* __restrict__ nf16, const int* __restrict__ offs,
    const unsigned* __restrict__ es, float* __restrict__ hn) {
  int tid = blockIdx.x * 256 + threadIdx.x;
  int node = tid >> 4;
  if (node >= N_NODES) return;
  int q = tid & 15;
  int beg = offs[node];
  int end = offs[node + 1];
  float acc[8];
#pragma unroll
  for (int j = 0; j < 8; ++j) acc[j] = 0.f;

  int k = beg;
  for (; k + 3 < end; k += 4) {
    unsigned r0 = es[k], r1 = es[k + 1], r2 = es[k + 2], r3 = es[k + 3];
    short8v v0 = *(const short8v*)(nf16 + (size_t)(r0 & 0xFFFF) * D + q * 8);
    short8v v1 = *(const short8v*)(nf16 + (size_t)(r1 & 0xFFFF) * D + q * 8);
    short8v v2 = *(const short8v*)(nf16 + (size_t)(r2 & 0xFFFF) * D + q * 8);
    short8v v3 = *(const short8v*)(nf16 + (size_t)(r3 & 0xFFFF) * D + q * 8);
    float w0 = bf2f((unsigned short)(r0 >> 16));
    float w1 = bf2f((unsigned short)(r1 >> 16));
    float w2 = bf2f((unsigned short)(r2 >> 16));
    float w3 = bf2f((unsigned short)(r3 >> 16));
#pragma unroll
    for (int j = 0; j < 8; ++j) {
      acc[j] += bf2f((unsigned short)v0[j]) * w0;
      acc[j] += bf2f((unsigned short)v1[j]) * w1;
      acc[j] += bf2f((unsigned short)v2[j]) * w2;
      acc[j] += bf2f((unsigned short)v3[j]) * w3;
    }
  }
  for (; k < end; ++k) {
    unsigned r0 = es[k];
    short8v v0 = *(const short8v*)(nf16 + (size_t)(r0 & 0xFFFF) * D + q * 8);
    float w0 = bf2f((unsigned short)(r0 >> 16));
#pragma unroll
    for (int j = 0; j < 8; ++j) acc[j] += bf2f((unsigned short)v0[j]) * w0;
  }

  float* orow = hn + (size_t)node * D + q * 8;
  *(float4*)(orow) = make_float4(acc[0], acc[1], acc[2], acc[3]);
  *(float4*)(orow + 4) = make_float4(acc[4], acc[5], acc[6], acc[7]);
}

// Mid-tier f32 gather (4B records).
__global__ __launch_bounds__(256) void gather_f32(
    const float* __restrict__ nfeat, const int* __restrict__ offs,
    const unsigned* __restrict__ es, float* __restrict__ hn) {
  int tid = blockIdx.x * 256 + threadIdx.x;
  int node = tid >> 5;
  if (node >= N_NODES) return;
  int q = tid & 31;
  int beg = offs[node];
  int end = offs[node + 1];
  float4 acc = {0.f, 0.f, 0.f, 0.f};
  int k = beg;
  for (; k + 1 < end; k += 2) {
    unsigned r0 = es[k], r1 = es[k + 1];
    float w0 = bf2f((unsigned short)(r0 >> 16));
    float w1 = bf2f((unsigned short)(r1 >> 16));
    float4 v0 = ((const float4*)(nfeat + (size_t)(r0 & 0xFFFF) * D))[q];
    float4 v1 = ((const float4*)(nfeat + (size_t)(r1 & 0xFFFF) * D))[q];
    acc.x += v0.x * w0 + v1.x * w1;
    acc.y += v0.y * w0 + v1.y * w1;
    acc.z += v0.z * w0 + v1.z * w1;
    acc.w += v0.w * w0 + v1.w * w1;
  }
  if (k < end) {
    unsigned r0 = es[k];
    float w0 = bf2f((unsigned short)(r0 >> 16));
    float4 v0 = ((const float4*)(nfeat + (size_t)(r0 & 0xFFFF) * D))[q];
    acc.x += v0.x * w0;
    acc.y += v0.y * w0;
    acc.z += v0.z * w0;
    acc.w += v0.w * w0;
  }
  ((float4*)(hn + (size_t)node * D))[q] = acc;
}

__global__ __launch_bounds__(256) void wconv(
    const float* __restrict__ W1, const float* __restrict__ W2,
    unsigned short* __restrict__ wc, int* __restrict__ cnt) {
  int i = blockIdx.x * 256 + threadIdx.x;
  if (i < D * D) {
    wc[i] = f2bf(W1[i]);
    wc[D * D + i] = f2bf(W2[i]);
  }
  if (i < N_NODES) cnt[i] = 0;
}

// ---------------------------------------------------------------------------
// Bi-interaction via 16x16x32 bf16 MFMA (templated on h dtype).
// ---------------------------------------------------------------------------
template <bool HBF16>
__global__ __launch_bounds__(256) void bi_mfma(
    const void* __restrict__ hsrc, const float* __restrict__ hn,
    const unsigned short* __restrict__ wc, float* __restrict__ out) {
  __shared__ __align__(16) unsigned short lds[2 * 64 * D];  // 32 KiB

  const int tid = threadIdx.x;
  const int lane = tid & 63;
  const int wid = tid >> 6;
  const int base = blockIdx.x * 64;
  const int r16 = lane & 15;
  const int kg = lane >> 4;

  short8v bf[2][2][4];
  {
    const int colbase = wid * 32;
#pragma unroll
    for (int g = 0; g < 2; ++g)
#pragma unroll
      for (int c = 0; c < 2; ++c)
#pragma unroll
        for (int ks = 0; ks < 4; ++ks) {
          int col = colbase + c * 16 + r16;
          int k = ks * 32 + kg * 8;
          bf[g][c][ks] =
              *(const short8v*)(wc + (size_t)g * D * D + (size_t)col * D + k);
        }
  }

#pragma unroll
  for (int p = 0; p < 8; ++p) {
    int flat = p * 1024 + tid * 4;
    int row = flat >> 7;
    int col = flat & 127;
    int node = base + row;
    float hx0 = 0.f, hx1 = 0.f, hx2 = 0.f, hx3 = 0.f;
    float4 nv = make_float4(0.f, 0.f, 0.f, 0.f);
    if (node < N_NODES) {
      if constexpr (HBF16) {
        short4v hv =
            *(const short4v*)((const unsigned short*)hsrc + (size_t)node * D + col);
        hx0 = bf2f((unsigned short)hv[0]);
        hx1 = bf2f((unsigned short)hv[1]);
        hx2 = bf2f((unsigned short)hv[2]);
        hx3 = bf2f((unsigned short)hv[3]);
      } else {
        float4 hv = *(const float4*)((const float*)hsrc + (size_t)node * D + col);
        hx0 = hv.x; hx1 = hv.y; hx2 = hv.z; hx3 = hv.w;
      }
      nv = *(const float4*)(hn + (size_t)node * D + col);
    }
    short4v av, mv;
    av[0] = (short)f2bf(hx0 + nv.x);
    av[1] = (short)f2bf(hx1 + nv.y);
    av[2] = (short)f2bf(hx2 + nv.z);
    av[3] = (short)f2bf(hx3 + nv.w);
    mv[0] = (short)f2bf(hx0 * nv.x);
    mv[1] = (short)f2bf(hx1 * nv.y);
    mv[2] = (short)f2bf(hx2 * nv.z);
    mv[3] = (short)f2bf(hx3 * nv.w);
    int boff = (row * 256 + col * 2) ^ ((row & 7) << 4);
    *(short4v*)((char*)lds + boff) = av;
    *(short4v*)((char*)lds + 16384 + boff) = mv;
  }
  __syncthreads();

  f32x4 acc1[4][2], acc2[4][2];
#pragma unroll
  for (int rt = 0; rt < 4; ++rt)
#pragma unroll
    for (int c = 0; c < 2; ++c) {
      acc1[rt][c] = (f32x4){0.f, 0.f, 0.f, 0.f};
      acc2[rt][c] = (f32x4){0.f, 0.f, 0.f, 0.f};
    }

#pragma unroll
  for (int ks = 0; ks < 4; ++ks) {
#pragma unroll
    for (int rt = 0; rt < 4; ++rt) {
      int row = rt * 16 + r16;
      int boff = (row * 256 + (ks * 32 + kg * 8) * 2) ^ ((row & 7) << 4);
      short8v a1 = *(const short8v*)((const char*)lds + boff);
      short8v a2 = *(const short8v*)((const char*)lds + 16384 + boff);
#pragma unroll
      for (int c = 0; c < 2; ++c) {
        acc1[rt][c] = __builtin_amdgcn_mfma_f32_16x16x32_bf16(
            a1, bf[0][c][ks], acc1[rt][c], 0, 0, 0);
        acc2[rt][c] = __builtin_amdgcn_mfma_f32_16x16x32_bf16(
            a2, bf[1][c][ks], acc2[rt][c], 0, 0, 0);
      }
    }
  }

#pragma unroll
  for (int rt = 0; rt < 4; ++rt) {
#pragma unroll
    for (int c = 0; c < 2; ++c) {
#pragma unroll
      for (int e = 0; e < 4; ++e) {
        int row = rt * 16 + kg * 4 + e;
        int node = base + row;
        if (node < N_NODES) {
          int col = wid * 32 + c * 16 + r16;
          float x1 = acc1[rt][c][e];
          float x2 = acc2[rt][c][e];
          x1 = x1 > 0.f ? x1 : 0.01f * x1;
          x2 = x2 > 0.f ? x2 : 0.01f * x2;
          out[(size_t)node * D + col] = x1 + x2;
        }
      }
    }
  }
}

// ---------------------------------------------------------------------------
// Tier-0 fallback (round-1 path).
// ---------------------------------------------------------------------------
__global__ __launch_bounds__(256) void edge_scatter(
    const float* __restrict__ nfeat, const float* __restrict__ w,
    const int* __restrict__ src, const int* __restrict__ dst,
    float* __restrict__ hn) {
  int tid = blockIdx.x * 256 + threadIdx.x;
  int e = tid >> 5;
  if (e >= N_EDGES) return;
  int q = tid & 31;
  int s = src[e];
  int d = dst[e];
  float we = w[e];
  float4 v = ((const float4*)(nfeat + (size_t)s * D))[q];
  float* drow = hn + (size_t)d * D + q * 4;
  atomicAdd(drow + 0, v.x * we);
  atomicAdd(drow + 1, v.y * we);
  atomicAdd(drow + 2, v.z * we);
  atomicAdd(drow + 3, v.w * we);
}

__global__ __launch_bounds__(256) void bi_inter(
    const float* __restrict__ h, const float* __restrict__ hn,
    const float* __restrict__ W1, const float* __restrict__ W2,
    float* __restrict__ out) {
  int wid = __builtin_amdgcn_readfirstlane(threadIdx.x >> 6);
  int lane = threadIdx.x & 63;
  int node = blockIdx.x * 64 + lane;
  if (node >= N_NODES) return;
  const float4* h4 = (const float4*)(h + (size_t)node * D);
  const float4* n4 = (const float4*)(hn + (size_t)node * D);
  float acc1[32], acc2[32];
#pragma unroll
  for (int j = 0; j < 32; ++j) { acc1[j] = 0.f; acc2[j] = 0.f; }
  const int obase = wid * 32;
  for (int kq = 0; kq < 32; ++kq) {
    float4 hv = h4[kq];
    float4 nv = n4[kq];
    float a0 = hv.x + nv.x, a1 = hv.y + nv.y, a2 = hv.z + nv.z, a3 = hv.w + nv.w;
    float m0 = hv.x * nv.x, m1 = hv.y * nv.y, m2 = hv.z * nv.z, m3 = hv.w * nv.w;
#pragma unroll
    for (int j = 0; j < 32; ++j) {
      int o = obase + j;
      float4 w1 = *(const float4*)(W1 + (size_t)o * D + kq * 4);
      float4 w2 = *(const float4*)(W2 + (size_t)o * D + kq * 4);
      acc1[j] += a0 * w1.x + a1 * w1.y + a2 * w1.z + a3 * w1.w;
      acc2[j] += m0 * w2.x + m1 * w2.y + m2 * w2.z + m3 * w2.w;
    }
  }
  float* orow = out + (size_t)node * D + obase;
#pragma unroll
  for (int j = 0; j < 32; j += 4) {
    float4 r;
    float x;
    x = acc1[j + 0]; x = x > 0.f ? x : 0.01f * x;
    r.x = x; x = acc2[j + 0]; x = x > 0.f ? x : 0.01f * x; r.x += x;
    x = acc1[j + 1]; x = x > 0.f ? x : 0.01f * x;
    r.y = x; x = acc2[j + 1]; x = x > 0.f ? x : 0.01f * x; r.y += x;
    x = acc1[j + 2]; x = x > 0.f ? x : 0.01f * x;
    r.z = x; x = acc2[j + 2]; x = x > 0.f ? x : 0.01f * x; r.z += x;
    x = acc1[j + 3]; x = x > 0.f ? x : 0.01f * x;
    r.w = x; x = acc2[j + 3]; x = x > 0.f ? x : 0.01f * x; r.w += x;
    *(float4*)(orow + j) = r;
  }
}

extern "C" void kernel_launch(void* const* d_in, const int* in_sizes, int n_in,
                              void* d_out, int out_size, void* d_ws, size_t ws_size,
                              hipStream_t stream) {
  const float* nfeat = (const float*)d_in[0];
  const float* w     = (const float*)d_in[1];
  const float* W1    = (const float*)d_in[2];
  const float* W2    = (const float*)d_in[3];
  const int*   src   = (const int*)d_in[4];
  const int*   dst   = (const int*)d_in[5];

  float* hn  = (float*)d_out;
  float* out = (float*)d_out + OUT0_ELEMS;

  // Workspace layout
  char* ws = (char*)d_ws;
  size_t off = 0;
  int* cnt = (int*)(ws + off);        off += (size_t)N_NODES * 4;
  int* offs = (int*)(ws + off);       off += (size_t)(N_NODES + 1) * 4;
  int* bsums = (int*)(ws + off);      off += 256 * 4;
  int* rank = (int*)(ws + off);       off += (size_t)N_EDGES * 4;
  unsigned* es = (unsigned*)(ws + off); off += (size_t)N_EDGES * 4;
  off = (off + 63) & ~(size_t)63;
  unsigned short* wc = (unsigned short*)(ws + off);
  off += (size_t)2 * D * D * 2;
  size_t tier1_bytes = off;
  off = (off + 63) & ~(size_t)63;
  unsigned short* nf16 = (unsigned short*)(ws + off);
  off += (size_t)N_NODES * D * 2;
  size_t tier2_bytes = off;

  if (ws_size < tier1_bytes) {
    // Tier 0: atomic scatter + VALU GEMM.
    hipMemsetAsync(hn, 0, (size_t)OUT0_ELEMS * sizeof(float), stream);
    long long threads = (long long)N_EDGES * 32;
    int blocks = (int)((threads + 255) / 256);
    edge_scatter<<<blocks, 256, 0, stream>>>(nfeat, w, src, dst, hn);
    bi_inter<<<(N_NODES + 63) / 64, 256, 0, stream>>>(nfeat, hn, W1, W2, out);
    return;
  }

  bool full = (ws_size >= tier2_bytes);

  if (full) {
    conv_all<<<N_NODES * D / 8 / 256, 256, 0, stream>>>(
        nfeat, W1, W2, nf16, wc, cnt);   // 3125 blocks exactly
  } else {
    wconv<<<(N_NODES + 255) / 256, 256, 0, stream>>>(W1, W2, wc, cnt);
  }
  hist_rank<<<N_EDGES / 4 / 256, 256, 0, stream>>>(dst, cnt, rank);  // 625 blocks
  scan_block<<<SCAN_BLOCKS, 256, 0, stream>>>(cnt, offs, bsums);
  scan_top<<<1, 256, 0, stream>>>(bsums);
  scan_finalize<<<SCAN_BLOCKS, 256, 0, stream>>>(offs, bsums);
  fill4<<<N_EDGES / 4 / 256, 256, 0, stream>>>(src, dst, w, rank, offs, es);

  if (full) {
    gather_bf16<<<(N_NODES * 16 + 255) / 256, 256, 0, stream>>>(nf16, offs, es, hn);
    bi_mfma<true><<<(N_NODES + 63) / 64, 256, 0, stream>>>(nf16, hn, wc, out);
  } else {
    gather_f32<<<(N_NODES * 32 + 255) / 256, 256, 0, stream>>>(nfeat, offs, es, hn);
    bi_mfma<false><<<(N_NODES + 63) / 64, 256, 0, stream>>>(nfeat, hn, wc, out);
  }
}